// Round 23
// baseline (1742.410 us; speedup 1.0000x reference)
//
#include <hip/hip_runtime.h>
#include <stdint.h>
#include <math.h>

namespace {

constexpr int kH = 160, kW = 160, kN = 8;
constexpr int kHW = kH * kW;              // 25600
constexpr int kM = kHW * 9;               // 230400 anchors / image
constexpr int kPre = 6000;
constexpr int kPost = 1000;
constexpr int kCand = 6016;
constexpr int kScr = 7168;                // bf16-screen candidates (10-sigma margin)
constexpr int kWords = 94;                // ceil(6016/64)
constexpr int kRowW = 96;                 // padded words per mask row
constexpr int kBmW = kM / 32;             // 7200 bitmap words
constexpr double kClampD = 4.135166556742356;  // np.log(1000/16) in f64

typedef short short8 __attribute__((ext_vector_type(8)));
typedef float f32x4 __attribute__((ext_vector_type(4)));

// base-anchor half extents — f32 (reference casts base anchors to f32).
__constant__ float c_hw[9] = {
  22.627416997969522f, 16.0f, 11.313708498984761f,
  45.254833995939045f, 32.0f, 22.627416997969522f,
  90.509667991878090f, 64.0f, 45.254833995939045f};
__constant__ float c_hh[9] = {
  11.313708498984761f, 16.0f, 22.627416997969522f,
  22.627416997969522f, 32.0f, 45.254833995939045f,
  45.254833995939045f, 64.0f, 90.509667991878090f};

__device__ __forceinline__ uint64_t ordd(double d) {
  uint64_t u = (uint64_t)__double_as_longlong(d);
  return (u >> 63) ? ~u : (u | 0x8000000000000000ull);
}
__device__ __forceinline__ unsigned ordf(float f) {
  unsigned u = __float_as_uint(f);
  return (u & 0x80000000u) ? ~u : (u | 0x80000000u);
}
__device__ __forceinline__ float4 ld4(const float* p) {
  return *reinterpret_cast<const float4*>(p);
}
__device__ __forceinline__ unsigned short f2bf(float f) {
  unsigned u = __float_as_uint(f);
  unsigned r = (u + 0x7FFFu + ((u >> 16) & 1u)) >> 16;   // RNE
  return (unsigned short)r;
}
__device__ __forceinline__ uint64_t shfl64(uint64_t v, int src) {
  unsigned lo = __shfl((unsigned)v, src);
  unsigned hi = __shfl((unsigned)(v >> 32), src);
  return ((uint64_t)hi << 32) | lo;
}

__device__ __forceinline__ void hist_add(unsigned* hist, unsigned bucket, bool active) {
  uint64_t same = __ballot(active ? 1 : 0);
  #pragma unroll
  for (int b = 0; b < 8; ++b) {
    uint64_t bb = __ballot((bucket >> b) & 1u);
    same &= ((bucket >> b) & 1u) ? bb : ~bb;
  }
  if (active) {
    int lane = (int)(threadIdx.x & 63);
    int leader = __ffsll((unsigned long long)same) - 1;
    if (lane == leader) atomicAdd(&hist[bucket], (unsigned)__popcll((unsigned long long)same));
  }
}

// Merged prep: wT4[R/4][oc][4] (f32 transpose) + wBf (bf16 MFMA B operand).
__global__ __launch_bounds__(256) void prep_kernel(
    const float* __restrict__ w1, float* __restrict__ wT4,
    short* __restrict__ wBf)
{
  int i = blockIdx.x * 256 + (int)threadIdx.x;
  if (i < 1152 * 128) {
    int R = i >> 7, oc = i & 127;
    wT4[(size_t)(R >> 2) * 512 + oc * 4 + (R & 3)] = w1[(size_t)oc * 1152 + R];
    int ic = i & 127, q = i >> 7;
    int oc2 = q & 127, k9 = q >> 7;
    wBf[i] = (short)f2bf(w1[(size_t)oc2 * 1152 + ic * 9 + k9]);
  }
}

// ========== bf16 MFMA SCREEN: conv3x3 + relu + cls head ====================
struct SConv {
  union {
    unsigned short A[3 * 162 * 32];   // 31104 B (MFMA phase)
    unsigned short X[160 * 136];      // 43520 B (head phase)
  } u;
  float w9[9][128];                   // 4608 B
};

__global__ __launch_bounds__(256) void conv_mfma_kernel(
    const float* __restrict__ feat, const short* __restrict__ wBf,
    const float* __restrict__ b1f, const float* __restrict__ cw,
    const float* __restrict__ cb, unsigned* __restrict__ scoresU)
{
  __shared__ SConv sm;
  const int h = blockIdx.x, n = blockIdx.y;
  const int t = threadIdx.x;
  const int lane = t & 63, wave = t >> 6;
  const int l15 = lane & 15, l4 = lane >> 4;
  const float* fbase = feat + (size_t)n * 128 * kHW;

  f32x4 acc[10][2];
  #pragma unroll
  for (int mf = 0; mf < 10; ++mf)
    #pragma unroll
    for (int nf = 0; nf < 2; ++nf)
      #pragma unroll
      for (int r = 0; r < 4; ++r) acc[mf][nf][r] = 0.f;

  for (int i = t; i < 1152; i += 256) sm.w9[i >> 7][i & 127] = cw[i];

  for (int ib = 0; ib < 4; ++ib) {
    __syncthreads();
    #pragma unroll
    for (int pair = 0; pair < 3; ++pair) {
      int p = wave + 4 * pair;          // 0..11
      int R = p >> 2, icb = p & 3;
      int hh = h - 1 + R;
      bool rowok = (unsigned)hh < (unsigned)kH;
      for (int pxi = 0; pxi < 3; ++pxi) {
        int px = lane + 64 * pxi;
        if (px >= 162) break;
        int w = px - 1;
        bool ok = rowok && (unsigned)w < (unsigned)kW;
        const float* gp = fbase + ((size_t)(ib * 32 + icb * 8) * kH + hh) * kW + w;
        short8 v;
        #pragma unroll
        for (int j = 0; j < 8; ++j) {
          float f = ok ? gp[(size_t)j * kHW] : 0.f;
          v[j] = (short)f2bf(f);
        }
        int row = R * 162 + px;
        int chunk = icb ^ (row & 3) ^ ((row >> 2) & 3);
        *(short8*)&sm.u.A[(row * 4 + chunk) * 8] = v;
      }
    }
    __syncthreads();
    const int myoc0 = wave * 32;
    for (int k9 = 0; k9 < 9; ++k9) {
      int ky = k9 / 3, kx = k9 - 3 * ky;
      const short* wb = wBf + ((size_t)k9 * 128 + myoc0 + l15) * 128 + ib * 32 + 8 * l4;
      short8 bf0 = *(const short8*)wb;
      short8 bf1 = *(const short8*)(wb + 16 * 128);
      #pragma unroll
      for (int mf = 0; mf < 10; ++mf) {
        int row = ky * 162 + mf * 16 + l15 + kx;
        int chunk = l4 ^ (row & 3) ^ ((row >> 2) & 3);
        short8 af = *(const short8*)&sm.u.A[(row * 4 + chunk) * 8];
        acc[mf][0] = __builtin_amdgcn_mfma_f32_16x16x32_bf16(af, bf0, acc[mf][0], 0, 0, 0);
        acc[mf][1] = __builtin_amdgcn_mfma_f32_16x16x32_bf16(af, bf1, acc[mf][1], 0, 0, 0);
      }
    }
  }
  __syncthreads();
  float b1v[2] = { b1f[wave * 32 + l15], b1f[wave * 32 + 16 + l15] };
  #pragma unroll
  for (int mf = 0; mf < 10; ++mf)
    #pragma unroll
    for (int nf = 0; nf < 2; ++nf) {
      int oc = wave * 32 + nf * 16 + l15;
      #pragma unroll
      for (int reg = 0; reg < 4; ++reg) {
        int px = mf * 16 + l4 * 4 + reg;
        float v = fmaxf(acc[mf][nf][reg] + b1v[nf], 0.f);
        sm.u.X[px * 136 + oc] = f2bf(v);
      }
    }
  __syncthreads();
  for (int idx = t; idx < 1440; idx += 256) {
    int o = idx / 160, px = idx - 160 * o;
    const float* wr = sm.w9[o];
    float s = 0.f;
    #pragma unroll 4
    for (int c8 = 0; c8 < 16; ++c8) {
      short8 xv = *(const short8*)&sm.u.X[px * 136 + c8 * 8];
      #pragma unroll
      for (int j = 0; j < 8; ++j) {
        float xf = __uint_as_float(((unsigned)(unsigned short)xv[j]) << 16);
        s = fmaf(xf, wr[c8 * 8 + j], s);
      }
    }
    scoresU[(size_t)n * kM + ((size_t)h * kW + px) * 9 + o] = ordf(s + cb[o]);
  }
}

// ==== top-kScr screen: 2 full scans (byte-hist + collect), exact select
// among the boundary-byte group (eq list); ascending emit via bitmap.
__global__ __launch_bounds__(1024) void screen_kernel(
    const unsigned* __restrict__ scoresU, unsigned* __restrict__ candIdx,
    unsigned* __restrict__ eqbuf)
{
  const int img = blockIdx.x;
  const unsigned* sc = scoresU + (size_t)img * kM;
  __shared__ unsigned hist[256];
  __shared__ unsigned bitmap[kBmW];     // 28800 B
  __shared__ unsigned ssum[1024];       // 4096 B
  __shared__ unsigned shv[8];
  const int t = threadIdx.x;
  for (int i = t; i < kBmW; i += 1024) bitmap[i] = 0;
  if (t < 256) hist[t] = 0;
  if (t < 8) shv[t] = 0;
  __syncthreads();
  // scan 1: top-byte histogram (ballot-aggregated; exponents cluster)
  #pragma unroll 4
  for (int i = t; i < kM; i += 1024) {
    unsigned u = sc[i];
    hist_add(hist, u >> 24, true);
  }
  __syncthreads();
  if (t == 0) {
    unsigned c = 0; int b = 255;
    for (; b > 0; --b) { unsigned hh = hist[b]; if (c + hh >= (unsigned)kScr) break; c += hh; }
    shv[0] = (unsigned)b;         // boundary byte b0
    shv[1] = (unsigned)kScr - c;  // needB within b0 group
    shv[2] = 0;                   // ce
  }
  __syncthreads();
  const unsigned b0 = shv[0];
  const unsigned needB = shv[1];
  unsigned* eq = eqbuf + (size_t)img * 8192;
  // scan 2: accept >b0 into bitmap; collect ==b0 indices to eq
  #pragma unroll 4
  for (int i = t; i < kM; i += 1024) {
    unsigned tb = sc[i] >> 24;
    if (tb > b0) {
      atomicOr(&bitmap[(unsigned)i >> 5], 1u << (i & 31));
    } else if (tb == b0) {
      unsigned p = atomicAdd(&shv[2], 1u);
      if (p < 8192u) eq[p] = (unsigned)i;
    }
  }
  __syncthreads();
  const unsigned ce = shv[2];
  if (ce <= 8192u) {
    // exact select among eq: 3x8-bit value radix (low 24 bits, desc)
    if (t == 0) { shv[3] = 0; shv[4] = 0; shv[5] = needB; }
    __syncthreads();
    for (int pass = 0; pass < 3; ++pass) {
      const int shift = 16 - pass * 8;
      if (t < 256) hist[t] = 0;
      __syncthreads();
      unsigned pre = shv[3], pm = shv[4];
      for (unsigned i = t; i < ce; i += 1024) {
        unsigned ul = sc[eq[i]] & 0x00FFFFFFu;
        if ((ul & pm) == pre) atomicAdd(&hist[(ul >> shift) & 255u], 1u);
      }
      __syncthreads();
      if (t == 0) {
        unsigned c = 0; int b = 255;
        for (; b > 0; --b) { unsigned hh = hist[b]; if (c + hh >= shv[5]) break; c += hh; }
        shv[3] |= ((unsigned)b) << shift;
        shv[4] |= 0xFFu << shift;
        shv[5] -= c;
      }
      __syncthreads();
    }
    const unsigned Tlow = shv[3];
    const unsigned needT = shv[5];
    for (unsigned i = t; i < ce; i += 1024) {
      unsigned idx = eq[i];
      if ((sc[idx] & 0x00FFFFFFu) > Tlow)
        atomicOr(&bitmap[idx >> 5], 1u << (idx & 31));
    }
    // tie: needT smallest indices among == Tlow (3x6-bit index radix)
    if (t == 0) { shv[6] = 0; shv[7] = 0; shv[2] = needT; }
    __syncthreads();
    for (int pass = 0; pass < 3; ++pass) {
      const int shift = 12 - pass * 6;
      if (t < 64) hist[t] = 0;
      __syncthreads();
      unsigned pre = shv[6], pm = shv[7];
      for (unsigned i = t; i < ce; i += 1024) {
        unsigned idx = eq[i];
        if ((sc[idx] & 0x00FFFFFFu) == Tlow && (idx & pm) == pre)
          atomicAdd(&hist[(idx >> shift) & 63u], 1u);
      }
      __syncthreads();
      if (t == 0) {
        unsigned c = 0; int b = 0;
        for (; b < 63; ++b) { unsigned hh = hist[b]; if (c + hh >= shv[2]) break; c += hh; }
        shv[6] |= ((unsigned)b) << shift;
        shv[7] |= 63u << shift;
        shv[2] -= c;
      }
      __syncthreads();
    }
    const unsigned tau = shv[6];
    for (unsigned i = t; i < ce; i += 1024) {
      unsigned idx = eq[i];
      if ((sc[idx] & 0x00FFFFFFu) == Tlow && idx <= tau)
        atomicOr(&bitmap[idx >> 5], 1u << (idx & 31));
    }
    __syncthreads();
  } else {
    // exact full-data fallback (never triggers on benign inputs)
    if (t == 0) { shv[3] = 0; shv[4] = 0; shv[5] = needB; }
    __syncthreads();
    for (int pass = 0; pass < 3; ++pass) {
      const int shift = 16 - pass * 8;
      if (t < 256) hist[t] = 0;
      __syncthreads();
      unsigned pre = shv[3], pm = shv[4];
      for (int i = t; i < kM; i += 1024) {
        unsigned u = sc[i];
        if ((u >> 24) == b0) {
          unsigned ul = u & 0x00FFFFFFu;
          if ((ul & pm) == pre) atomicAdd(&hist[(ul >> shift) & 255u], 1u);
        }
      }
      __syncthreads();
      if (t == 0) {
        unsigned c = 0; int b = 255;
        for (; b > 0; --b) { unsigned hh = hist[b]; if (c + hh >= shv[5]) break; c += hh; }
        shv[3] |= ((unsigned)b) << shift;
        shv[4] |= 0xFFu << shift;
        shv[5] -= c;
      }
      __syncthreads();
    }
    const unsigned Tlow = shv[3];
    const unsigned needT = shv[5];
    for (int i = t; i < kM; i += 1024) {
      unsigned u = sc[i];
      if ((u >> 24) == b0 && (u & 0x00FFFFFFu) > Tlow)
        atomicOr(&bitmap[(unsigned)i >> 5], 1u << (i & 31));
    }
    if (t == 0) { shv[6] = 0; shv[7] = 0; shv[2] = needT; }
    __syncthreads();
    for (int pass = 0; pass < 3; ++pass) {
      const int shift = 12 - pass * 6;
      if (t < 64) hist[t] = 0;
      __syncthreads();
      unsigned pre = shv[6], pm = shv[7];
      for (int i = t; i < kM; i += 1024) {
        unsigned u = sc[i];
        if ((u >> 24) == b0 && (u & 0x00FFFFFFu) == Tlow &&
            (((unsigned)i) & pm) == pre)
          atomicAdd(&hist[(((unsigned)i) >> shift) & 63u], 1u);
      }
      __syncthreads();
      if (t == 0) {
        unsigned c = 0; int b = 0;
        for (; b < 63; ++b) { unsigned hh = hist[b]; if (c + hh >= shv[2]) break; c += hh; }
        shv[6] |= ((unsigned)b) << shift;
        shv[7] |= 63u << shift;
        shv[2] -= c;
      }
      __syncthreads();
    }
    const unsigned tau = shv[6];
    for (int i = t; i < kM; i += 1024) {
      unsigned u = sc[i];
      if ((u >> 24) == b0 && (u & 0x00FFFFFFu) == Tlow && (unsigned)i <= tau)
        atomicOr(&bitmap[(unsigned)i >> 5], 1u << (i & 31));
    }
    __syncthreads();
  }
  // emit set bits ascending: popcount + Hillis-Steele block scan
  unsigned cl = 0;
  #pragma unroll
  for (int k = 0; k < 8; ++k) {
    int wi = t * 8 + k;
    if (wi < kBmW) cl += (unsigned)__popc(bitmap[wi]);
  }
  ssum[t] = cl;
  __syncthreads();
  for (int o2 = 1; o2 < 1024; o2 <<= 1) {
    unsigned v = (t >= o2) ? ssum[t - o2] : 0u;
    __syncthreads();
    ssum[t] += v;
    __syncthreads();
  }
  unsigned off = ssum[t] - cl;
  unsigned* tout = candIdx + (size_t)img * kScr;
  #pragma unroll
  for (int k = 0; k < 8; ++k) {
    int wi = t * 8 + k;
    if (wi < kBmW) {
      unsigned wv = bitmap[wi];
      while (wv) {
        int b = __ffs(wv) - 1;
        wv &= wv - 1;
        tout[off++] = (unsigned)(wi * 32 + b);
      }
    }
  }
}

// ==== f64 refine: 6 cands/block; f32 patch in LDS (lossless), cvt at use.
// 256 thr = 32 oc-base x 8 K-eighths; 4 oc/thread. sBase splits the range.
__global__ __launch_bounds__(256) void refine_kernel(
    const float* __restrict__ feat, const float* __restrict__ wT4,
    const float* __restrict__ b1, const float* __restrict__ cw,
    const float* __restrict__ cb, const float* __restrict__ bwp,
    const float* __restrict__ bbp, const unsigned* __restrict__ candIdx,
    double* __restrict__ rsc, double* __restrict__ rdd, int sBase)
{
  const int img = blockIdx.y;
  const int s0 = sBase + blockIdx.x * 6;
  const int t = threadIdx.x;
  __shared__ __align__(16) float patch[6][1160];   // 27840 B
  __shared__ double xa[128][6];                    // 6144 B
  __shared__ double dd[6][5];
  __shared__ unsigned meta[6];
  if (t < 6) {
    int s = s0 + t;
    meta[t] = candIdx[(size_t)img * kScr + (s < kScr ? s : kScr - 1)];
  }
  __syncthreads();
  const float* fb = feat + (size_t)img * 128 * kHW;
  for (int e = t; e < 6 * 384; e += 256) {
    int rr = e / 384, q = e % 384, ic = q / 3, ky = q % 3;
    unsigned idx = meta[rr];
    int pix = (int)(idx / 9u);
    int hh = pix / kW - 1 + ky, ww = pix % kW;
    float v0 = 0.f, v1 = 0.f, v2 = 0.f;
    if ((unsigned)hh < (unsigned)kH) {
      const float* row = fb + ((size_t)ic * kH + hh) * kW + ww;
      if (ww - 1 >= 0) v0 = row[-1];
      v1 = row[0];
      if (ww + 1 < kW) v2 = row[1];
    }
    float* pp = &patch[rr][ic * 9 + ky * 3];
    pp[0] = v0; pp[1] = v1; pp[2] = v2;
  }
  __syncthreads();
  const int ocb = t & 31, rh = t >> 5;   // oc = ocb + 32*k; K-eighth rh
  double acc[4][6];
  #pragma unroll
  for (int k = 0; k < 4; ++k)
    #pragma unroll
    for (int c = 0; c < 6; ++c) acc[k][c] = 0.0;
  {
    const float4* wq = reinterpret_cast<const float4*>(wT4) + (size_t)(rh * 36) * 128;
    for (int R4 = 0; R4 < 36; ++R4) {
      float4 wv0 = wq[(size_t)R4 * 128 + ocb];
      float4 wv1 = wq[(size_t)R4 * 128 + ocb + 32];
      float4 wv2 = wq[(size_t)R4 * 128 + ocb + 64];
      float4 wv3 = wq[(size_t)R4 * 128 + ocb + 96];
      double w0x = (double)wv0.x, w0y = (double)wv0.y, w0z = (double)wv0.z, w0w = (double)wv0.w;
      double w1x = (double)wv1.x, w1y = (double)wv1.y, w1z = (double)wv1.z, w1w = (double)wv1.w;
      double w2x = (double)wv2.x, w2y = (double)wv2.y, w2z = (double)wv2.z, w2w = (double)wv2.w;
      double w3x = (double)wv3.x, w3y = (double)wv3.y, w3z = (double)wv3.z, w3w = (double)wv3.w;
      const int Rp = rh * 144 + R4 * 4;
      #pragma unroll
      for (int c = 0; c < 6; ++c) {
        float4 pv = *reinterpret_cast<const float4*>(&patch[c][Rp]);
        double p0 = (double)pv.x, p1 = (double)pv.y,
               p2 = (double)pv.z, p3 = (double)pv.w;
        acc[0][c] = fma(w0x, p0, acc[0][c]);
        acc[0][c] = fma(w0y, p1, acc[0][c]);
        acc[0][c] = fma(w0z, p2, acc[0][c]);
        acc[0][c] = fma(w0w, p3, acc[0][c]);
        acc[1][c] = fma(w1x, p0, acc[1][c]);
        acc[1][c] = fma(w1y, p1, acc[1][c]);
        acc[1][c] = fma(w1z, p2, acc[1][c]);
        acc[1][c] = fma(w1w, p3, acc[1][c]);
        acc[2][c] = fma(w2x, p0, acc[2][c]);
        acc[2][c] = fma(w2y, p1, acc[2][c]);
        acc[2][c] = fma(w2z, p2, acc[2][c]);
        acc[2][c] = fma(w2w, p3, acc[2][c]);
        acc[3][c] = fma(w3x, p0, acc[3][c]);
        acc[3][c] = fma(w3y, p1, acc[3][c]);
        acc[3][c] = fma(w3z, p2, acc[3][c]);
        acc[3][c] = fma(w3w, p3, acc[3][c]);
      }
    }
  }
  #pragma unroll
  for (int g = 0; g < 8; ++g) {
    if (rh == g) {
      #pragma unroll
      for (int k = 0; k < 4; ++k)
        #pragma unroll
        for (int c = 0; c < 6; ++c) {
          if (g == 0) xa[ocb + 32 * k][c] = acc[k][c];
          else        xa[ocb + 32 * k][c] += acc[k][c];
        }
    }
    __syncthreads();
  }
  if (rh == 0) {
    #pragma unroll
    for (int k = 0; k < 4; ++k) {
      double bb1 = (double)b1[ocb + 32 * k];
      #pragma unroll
      for (int c = 0; c < 6; ++c)
        xa[ocb + 32 * k][c] = fmax(xa[ocb + 32 * k][c] + bb1, 0.0);
    }
  }
  __syncthreads();
  if (t < 30) {
    int rr = t % 6, j = t / 6;   // j in 0..4 (4 deltas + 1 score)
    unsigned idx = meta[rr];
    int a = (int)(idx % 9u);
    const float* wr = (j < 4) ? (bwp + (size_t)(a * 4 + j) * 128)
                              : (cw + (size_t)a * 128);
    double s = 0.0;
    for (int c = 0; c < 128; ++c) s = fma((double)wr[c], xa[c][rr], s);
    dd[rr][j] = s + (double)((j < 4) ? bbp[a * 4 + j] : cb[a]);
  }
  __syncthreads();
  if (t < 6 && s0 + t < kScr) {
    size_t s = (size_t)img * kScr + s0 + t;
    rsc[s] = dd[t][4];
    double* rd = rdd + s * 4;
    rd[0] = dd[t][0]; rd[1] = dd[t][1]; rd[2] = dd[t][2]; rd[3] = dd[t][3];
  }
}

// == exact top-6000 select + sort (f64 desc, anchor-idx asc) + decode ======
__global__ __launch_bounds__(1024) void select_sort_decode_kernel(
    const double* __restrict__ rsc, const double* __restrict__ rdd,
    const unsigned* __restrict__ candIdx, const int* __restrict__ imgsz,
    double* __restrict__ cand)
{
  const int img = blockIdx.x;
  const int t = threadIdx.x;
  __shared__ uint64_t k64[8192];
  __shared__ unsigned id32[8192];   // (anchorIdx<<13) | slot
  for (int j = t; j < 8192; j += 1024) {
    if (j < kScr) {
      k64[j] = ordd(rsc[(size_t)img * kScr + j]);
      id32[j] = (candIdx[(size_t)img * kScr + j] << 13) | (unsigned)j;
    } else { k64[j] = 0; id32[j] = 0xFFFFFFFFu; }
  }
  __syncthreads();
  for (unsigned kk = 2; kk <= 8192; kk <<= 1) {
    for (unsigned jj = kk >> 1; jj > 0; jj >>= 1) {
      for (unsigned i = t; i < 8192; i += 1024) {
        unsigned ixj = i ^ jj;
        if (ixj > i) {
          uint64_t ka = k64[i], kb = k64[ixj];
          unsigned ia = id32[i], ib = id32[ixj];
          bool desc = ((i & kk) == 0);
          bool amis = (ka < kb) || (ka == kb && ia > ib);
          if (desc ? amis : !amis) {
            k64[i] = kb; k64[ixj] = ka;
            id32[i] = ib; id32[ixj] = ia;
          }
        }
      }
      __syncthreads();
    }
  }
  double* cx1 = cand + (size_t)img * 6 * kCand;
  double* cy1 = cx1 + kCand; double* cx2 = cy1 + kCand; double* cy2 = cx2 + kCand;
  double* car = cy2 + kCand; double* csc = car + kCand;
  const double img_f = (double)imgsz[0];
  const double stride = floor(img_f / (double)kW + 0.5);
  for (int r = t; r < kCand; r += 1024) {
    if (r < kPre) {
      unsigned id = id32[r];
      unsigned slot = id & 8191u;
      unsigned aidx = id >> 13;
      int a = (int)(aidx % 9u);
      int pix = (int)(aidx / 9u);
      int hh = pix / kW, ww = pix % kW;
      double sx = (double)ww * stride, sy = (double)hh * stride;
      double hwd = (double)c_hw[a], hhd = (double)c_hh[a];
      double a0 = sx - hwd, a1 = sy - hhd, a2 = sx + hwd, a3 = sy + hhd;
      double wa = a2 - a0, ha = a3 - a1;
      double cxa = a0 + 0.5 * wa, cya = a1 + 0.5 * ha;
      const double* d = rdd + ((size_t)img * kScr + slot) * 4;
      double dx = d[0], dy = d[1];
      double dw = fmin(d[2], kClampD), dh = fmin(d[3], kClampD);
      double cx = dx * wa + cxa, cy = dy * ha + cya;
      double bw2 = exp(dw) * wa, bh2 = exp(dh) * ha;
      double x1 = cx - 0.5 * bw2, y1 = cy - 0.5 * bh2;
      double x2 = cx + 0.5 * bw2, y2 = cy + 0.5 * bh2;
      x1 = fmin(fmax(x1, 0.0), img_f); y1 = fmin(fmax(y1, 0.0), img_f);
      x2 = fmin(fmax(x2, 0.0), img_f); y2 = fmin(fmax(y2, 0.0), img_f);
      cx1[r] = x1; cy1[r] = y1; cx2[r] = x2; cy2[r] = y2;
      car[r] = (x2 - x1) * (y2 - y1);
      csc[r] = rsc[(size_t)img * kScr + slot];
    } else {
      cx1[r] = 0.0; cy1[r] = 0.0; cx2[r] = 0.0; cy2[r] = 0.0;
      car[r] = 0.0; csc[r] = -1e9;
    }
  }
}

// ==== NMS mask: f32 fast path + rigorous f64 fallback (|lhs| < 32) ========
__global__ __launch_bounds__(64) void mask_kernel(
    const double* __restrict__ cand, uint64_t* __restrict__ mask)
{
  const int img = blockIdx.z, bi = blockIdx.y, b8 = blockIdx.x;
  if (bi >= (b8 + 1) * 8) return;
  const int i = bi * 64 + (int)threadIdx.x;
  const double* cx1 = cand + (size_t)img * 6 * kCand;
  const double* cy1 = cx1 + kCand; const double* cx2 = cy1 + kCand;
  const double* cy2 = cx2 + kCand; const double* car = cy2 + kCand;
  __shared__ float jb[5][512];
  const int j0base = b8 * 512;
  for (int e = (int)threadIdx.x; e < 512; e += 64) {
    int j = j0base + e; if (j >= kCand) j = kCand - 1;
    jb[0][e] = (float)cx1[j]; jb[1][e] = (float)cy1[j];
    jb[2][e] = (float)cx2[j]; jb[3][e] = (float)cy2[j];
    jb[4][e] = (float)car[j];
  }
  const double x1d = cx1[i], y1d = cy1[i], x2d = cx2[i], y2d = cy2[i], ard = car[i];
  const float fx1 = (float)x1d, fy1 = (float)y1d, fx2 = (float)x2d,
              fy2 = (float)y2d, far2 = (float)ard;
  __syncthreads();
  uint64_t row[8];
  #pragma unroll
  for (int wi = 0; wi < 8; ++wi) {
    const int w = b8 * 8 + wi;
    uint64_t bits = 0;
    if (w < kWords) {
      const int e0 = wi * 64;
      uint64_t amb = 0;
      for (int jj = 0; jj < 64; ++jj) {
        const int e = e0 + jj;
        float ix1 = fmaxf(fx1, jb[0][e]);
        float iy1 = fmaxf(fy1, jb[1][e]);
        float ix2 = fminf(fx2, jb[2][e]);
        float iy2 = fminf(fy2, jb[3][e]);
        float inter = fmaxf(ix2 - ix1, 0.f) * fmaxf(iy2 - iy1, 0.f);
        float den = fmaxf(far2 + jb[4][e] - inter, 1e-9f);
        float lhs = fmaf(-0.7f, den, inter);
        bits |= (uint64_t)(lhs > 0.f) << jj;
        amb  |= (uint64_t)(fabsf(lhs) < 32.f) << jj;
      }
      while (amb) {
        int jj = __ffsll((unsigned long long)amb) - 1;
        amb &= amb - 1;
        int j = j0base + wi * 64 + jj;
        double ix1 = fmax(x1d, cx1[j]);
        double iy1 = fmax(y1d, cy1[j]);
        double ix2 = fmin(x2d, cx2[j]);
        double iy2 = fmin(y2d, cy2[j]);
        double inter = fmax(ix2 - ix1, 0.0) * fmax(iy2 - iy1, 0.0);
        double den = fmax(ard + car[j] - inter, 1e-9);
        uint64_t bit = (uint64_t)(inter > 0.7 * den);
        bits = (bits & ~(1ull << jj)) | (bit << jj);
      }
    }
    row[wi] = bits;
  }
  uint64_t* rp = mask + ((size_t)img * kCand + i) * kRowW + b8 * 8;
  #pragma unroll
  for (int wi = 0; wi < 8; ++wi)
    if (b8 * 8 + wi < kWords) rp[wi] = row[wi];
}

// ===== greedy scan: 4 waves, double-buffered staging; wave 0 walks batch b
// while waves 1-3 stage batch b+1.
__global__ __launch_bounds__(256) void scan_kernel(
    const double* __restrict__ cand, const uint64_t* __restrict__ mask,
    float* __restrict__ out)
{
  const int img = blockIdx.x;
  const int t = threadIdx.x;
  const int lane = t & 63, wave = t >> 6;
  __shared__ uint64_t rows[2][64][96];    // 98304 B
  __shared__ unsigned short keep[kPost];  // 2000 B
  __shared__ int sh_cnt;
  if (t == 0) sh_cnt = 0;
  const uint64_t* mb = mask + (size_t)img * kCand * kRowW;
  const bool hiValid = (lane + 64 < kWords);
  uint64_t remLo = 0, remHi = 0;
  int cnt = 0;

  {
    uint64_t tl[16], th[16];
    #pragma unroll
    for (int i = 0; i < 16; ++i) {
      const uint64_t* rp = mb + (size_t)(wave + 4 * i) * kRowW;
      tl[i] = rp[lane];
      th[i] = hiValid ? rp[lane + 64] : 0ull;
    }
    #pragma unroll
    for (int i = 0; i < 16; ++i) {
      int r = wave + 4 * i;
      rows[0][r][lane] = tl[i];
      if (hiValid) rows[0][r][lane + 64] = th[i];
    }
  }
  __syncthreads();

  int cur = 0;
  for (int b = 0; b < kWords; ++b) {
    if (wave != 0) {
      int nb = b + 1;
      if (nb < kWords) {
        const uint64_t* rb = mb + (size_t)nb * 64 * kRowW;
        uint64_t tl[22], th[22];
        #pragma unroll
        for (int i = 0; i < 22; ++i) {
          int r = (wave - 1) + 3 * i;
          if (r < 64) {
            const uint64_t* rp = rb + (size_t)r * kRowW;
            tl[i] = rp[lane];
            th[i] = hiValid ? rp[lane + 64] : 0ull;
          }
        }
        #pragma unroll
        for (int i = 0; i < 22; ++i) {
          int r = (wave - 1) + 3 * i;
          if (r < 64) {
            rows[cur ^ 1][r][lane] = tl[i];
            if (hiValid) rows[cur ^ 1][r][lane + 64] = th[i];
          }
        }
      }
    } else {
      uint64_t rw = (b < 64) ? remLo : remHi;
      uint64_t aliveW = ~shfl64(rw, b & 63);
      if (b == kWords - 1) aliveW &= (1ull << 48) - 1ull;   // kPre = 93*64+48
      while (aliveW != 0ull && cnt < kPost) {
        int i = __ffsll((unsigned long long)aliveW) - 1;
        if (lane == 0) keep[cnt] = (unsigned short)(b * 64 + i);
        ++cnt;
        remLo |= rows[cur][i][lane];
        if (hiValid) remHi |= rows[cur][i][lane + 64];
        aliveW &= ~(1ull << i);
        aliveW &= ~rows[cur][i][b];
      }
      if (lane == 0) sh_cnt = cnt;
    }
    __syncthreads();
    if (sh_cnt >= kPost) break;
    cur ^= 1;
  }

  __syncthreads();
  const int fcnt = sh_cnt;
  const double* cx1 = cand + (size_t)img * 6 * kCand;
  const double* cy1 = cx1 + kCand; const double* cx2 = cy1 + kCand;
  const double* cy2 = cx2 + kCand; const double* car = cy2 + kCand;
  const double* csc = car + kCand;
  for (int r = t; r < kPost; r += 256) {
    float b0 = 0.f, b1v = 0.f, b2 = 0.f, b3 = 0.f, s = -1e9f;
    if (r < fcnt) {
      int i = keep[r];
      b0 = (float)cx1[i]; b1v = (float)cy1[i];
      b2 = (float)cx2[i]; b3 = (float)cy2[i]; s = (float)csc[i];
    }
    float* ob = out + ((size_t)img * kPost + r) * 4;
    ob[0] = b0; ob[1] = b1v; ob[2] = b2; ob[3] = b3;
    out[(size_t)kN * kPost * 4 + (size_t)img * kPost + r] = s;
  }
}

}  // namespace

extern "C" void kernel_launch(void* const* d_in, const int* in_sizes, int n_in,
                              void* d_out, int out_size, void* d_ws, size_t ws_size,
                              hipStream_t stream) {
  const float* feat = (const float*)d_in[0];
  const float* w1   = (const float*)d_in[1];
  const float* b1   = (const float*)d_in[2];
  const float* cw   = (const float*)d_in[3];
  const float* cb   = (const float*)d_in[4];
  const float* bwp  = (const float*)d_in[5];
  const float* bbp  = (const float*)d_in[6];
  const int*   imgsz = (const int*)d_in[7];
  float* out = (float*)d_out;
  char* ws = (char*)d_ws;

  size_t off = 0;
  auto take = [&](size_t sz) { size_t o = off; off += (sz + 255) & ~(size_t)255; return o; };
  size_t oWT4    = take((size_t)1152 * 128 * 4);
  size_t oWBf    = take((size_t)9 * 128 * 128 * 2);
  size_t oScrU   = take((size_t)kN * kM * 4);
  size_t oCandI  = take((size_t)kN * kScr * 4);
  size_t oEq     = take((size_t)kN * 8192 * 4);
  size_t oRsc    = take((size_t)kN * kScr * 8);
  size_t oRdd    = take((size_t)kN * kScr * 4 * 8);
  size_t oCand   = take((size_t)kN * 6 * kCand * 8);
  size_t oMask   = take((size_t)kN * kCand * kRowW * 8);
  if (ws_size < off) return;

  float*    wT4     = (float*)(ws + oWT4);
  short*    wBf     = (short*)(ws + oWBf);
  unsigned* scoresU = (unsigned*)(ws + oScrU);
  unsigned* candI   = (unsigned*)(ws + oCandI);
  unsigned* eqb     = (unsigned*)(ws + oEq);
  double*   rsc     = (double*)(ws + oRsc);
  double*   rdd     = (double*)(ws + oRdd);
  double*   cand    = (double*)(ws + oCand);
  uint64_t* mask    = (uint64_t*)(ws + oMask);

  hipLaunchKernelGGL(prep_kernel, dim3(576), dim3(256), 0, stream, w1, wT4, wBf);
  hipLaunchKernelGGL(conv_mfma_kernel, dim3(kH, kN), dim3(256), 0, stream,
                     feat, wBf, b1, cw, cb, scoresU);
  hipLaunchKernelGGL(screen_kernel, dim3(kN), dim3(1024), 0, stream,
                     scoresU, candI, eqb);
  hipLaunchKernelGGL(refine_kernel, dim3(598, kN), dim3(256), 0, stream,
                     feat, wT4, b1, cw, cb, bwp, bbp, candI, rsc, rdd, 0);
  hipLaunchKernelGGL(refine_kernel, dim3(597, kN), dim3(256), 0, stream,
                     feat, wT4, b1, cw, cb, bwp, bbp, candI, rsc, rdd, 3588);
  hipLaunchKernelGGL(select_sort_decode_kernel, dim3(kN), dim3(1024), 0, stream,
                     rsc, rdd, candI, imgsz, cand);
  hipLaunchKernelGGL(mask_kernel, dim3(12, kWords, kN), dim3(64), 0, stream,
                     cand, mask);
  hipLaunchKernelGGL(scan_kernel, dim3(kN), dim3(256), 0, stream,
                     cand, mask, out);
}

// Round 24
// 1375.418 us; speedup vs baseline: 1.2668x; 1.2668x over previous
//
#include <hip/hip_runtime.h>
#include <stdint.h>
#include <math.h>

namespace {

constexpr int kH = 160, kW = 160, kN = 8;
constexpr int kHW = kH * kW;              // 25600
constexpr int kM = kHW * 9;               // 230400 anchors / image
constexpr int kPre = 6000;
constexpr int kPost = 1000;
constexpr int kCand = 6016;
constexpr int kScr = 7168;                // bf16-screen candidates (10-sigma margin)
constexpr int kWords = 94;                // ceil(6016/64)
constexpr int kRowW = 96;                 // padded words per mask row
constexpr int kBmW = kM / 32;             // 7200 bitmap words
constexpr double kClampD = 4.135166556742356;  // np.log(1000/16) in f64

typedef short short8 __attribute__((ext_vector_type(8)));
typedef float f32x4 __attribute__((ext_vector_type(4)));

__constant__ float c_hw[9] = {
  22.627416997969522f, 16.0f, 11.313708498984761f,
  45.254833995939045f, 32.0f, 22.627416997969522f,
  90.509667991878090f, 64.0f, 45.254833995939045f};
__constant__ float c_hh[9] = {
  11.313708498984761f, 16.0f, 22.627416997969522f,
  22.627416997969522f, 32.0f, 45.254833995939045f,
  45.254833995939045f, 64.0f, 90.509667991878090f};

__device__ __forceinline__ uint64_t ordd(double d) {
  uint64_t u = (uint64_t)__double_as_longlong(d);
  return (u >> 63) ? ~u : (u | 0x8000000000000000ull);
}
__device__ __forceinline__ unsigned ordf(float f) {
  unsigned u = __float_as_uint(f);
  return (u & 0x80000000u) ? ~u : (u | 0x80000000u);
}
__device__ __forceinline__ float4 ld4(const float* p) {
  return *reinterpret_cast<const float4*>(p);
}
__device__ __forceinline__ unsigned short f2bf(float f) {
  unsigned u = __float_as_uint(f);
  unsigned r = (u + 0x7FFFu + ((u >> 16) & 1u)) >> 16;   // RNE
  return (unsigned short)r;
}
__device__ __forceinline__ uint64_t shfl64(uint64_t v, int src) {
  unsigned lo = __shfl((unsigned)v, src);
  unsigned hi = __shfl((unsigned)(v >> 32), src);
  return ((uint64_t)hi << 32) | lo;
}

// Merged prep: wT4[R/4][oc][4] (f32 transpose) + wBf (bf16 MFMA B operand).
__global__ __launch_bounds__(256) void prep_kernel(
    const float* __restrict__ w1, float* __restrict__ wT4,
    short* __restrict__ wBf)
{
  int i = blockIdx.x * 256 + (int)threadIdx.x;
  if (i < 1152 * 128) {
    int R = i >> 7, oc = i & 127;
    wT4[(size_t)(R >> 2) * 512 + oc * 4 + (R & 3)] = w1[(size_t)oc * 1152 + R];
    int ic = i & 127, q = i >> 7;
    int oc2 = q & 127, k9 = q >> 7;
    wBf[i] = (short)f2bf(w1[(size_t)oc2 * 1152 + ic * 9 + k9]);
  }
}

// zero hist16 (kN*65536) + bitmap (kN*kBmW) + thr (kN*8)
__global__ __launch_bounds__(256) void zero_kernel(
    unsigned* __restrict__ hist16, unsigned* __restrict__ bmG,
    unsigned* __restrict__ thrG)
{
  int i = blockIdx.x * 256 + (int)threadIdx.x;
  int nh = kN * 65536;
  int nb = kN * kBmW;
  if (i < nh) hist16[i] = 0;
  if (i < nb) bmG[i] = 0;
  if (i < kN * 8) thrG[i] = 0;
}

// ========== bf16 MFMA SCREEN: conv3x3 + relu + cls head ====================
struct SConv {
  union {
    unsigned short A[3 * 162 * 32];   // 31104 B (MFMA phase)
    unsigned short X[160 * 136];      // 43520 B (head phase)
  } u;
  float w9[9][128];                   // 4608 B
};

__global__ __launch_bounds__(256) void conv_mfma_kernel(
    const float* __restrict__ feat, const short* __restrict__ wBf,
    const float* __restrict__ b1f, const float* __restrict__ cw,
    const float* __restrict__ cb, unsigned* __restrict__ scoresU)
{
  __shared__ SConv sm;
  const int h = blockIdx.x, n = blockIdx.y;
  const int t = threadIdx.x;
  const int lane = t & 63, wave = t >> 6;
  const int l15 = lane & 15, l4 = lane >> 4;
  const float* fbase = feat + (size_t)n * 128 * kHW;

  f32x4 acc[10][2];
  #pragma unroll
  for (int mf = 0; mf < 10; ++mf)
    #pragma unroll
    for (int nf = 0; nf < 2; ++nf)
      #pragma unroll
      for (int r = 0; r < 4; ++r) acc[mf][nf][r] = 0.f;

  for (int i = t; i < 1152; i += 256) sm.w9[i >> 7][i & 127] = cw[i];

  for (int ib = 0; ib < 4; ++ib) {
    __syncthreads();
    #pragma unroll
    for (int pair = 0; pair < 3; ++pair) {
      int p = wave + 4 * pair;          // 0..11
      int R = p >> 2, icb = p & 3;
      int hh = h - 1 + R;
      bool rowok = (unsigned)hh < (unsigned)kH;
      for (int pxi = 0; pxi < 3; ++pxi) {
        int px = lane + 64 * pxi;
        if (px >= 162) break;
        int w = px - 1;
        bool ok = rowok && (unsigned)w < (unsigned)kW;
        const float* gp = fbase + ((size_t)(ib * 32 + icb * 8) * kH + hh) * kW + w;
        short8 v;
        #pragma unroll
        for (int j = 0; j < 8; ++j) {
          float f = ok ? gp[(size_t)j * kHW] : 0.f;
          v[j] = (short)f2bf(f);
        }
        int row = R * 162 + px;
        int chunk = icb ^ (row & 3) ^ ((row >> 2) & 3);
        *(short8*)&sm.u.A[(row * 4 + chunk) * 8] = v;
      }
    }
    __syncthreads();
    const int myoc0 = wave * 32;
    for (int k9 = 0; k9 < 9; ++k9) {
      int ky = k9 / 3, kx = k9 - 3 * ky;
      const short* wb = wBf + ((size_t)k9 * 128 + myoc0 + l15) * 128 + ib * 32 + 8 * l4;
      short8 bf0 = *(const short8*)wb;
      short8 bf1 = *(const short8*)(wb + 16 * 128);
      #pragma unroll
      for (int mf = 0; mf < 10; ++mf) {
        int row = ky * 162 + mf * 16 + l15 + kx;
        int chunk = l4 ^ (row & 3) ^ ((row >> 2) & 3);
        short8 af = *(const short8*)&sm.u.A[(row * 4 + chunk) * 8];
        acc[mf][0] = __builtin_amdgcn_mfma_f32_16x16x32_bf16(af, bf0, acc[mf][0], 0, 0, 0);
        acc[mf][1] = __builtin_amdgcn_mfma_f32_16x16x32_bf16(af, bf1, acc[mf][1], 0, 0, 0);
      }
    }
  }
  __syncthreads();
  float b1v[2] = { b1f[wave * 32 + l15], b1f[wave * 32 + 16 + l15] };
  #pragma unroll
  for (int mf = 0; mf < 10; ++mf)
    #pragma unroll
    for (int nf = 0; nf < 2; ++nf) {
      int oc = wave * 32 + nf * 16 + l15;
      #pragma unroll
      for (int reg = 0; reg < 4; ++reg) {
        int px = mf * 16 + l4 * 4 + reg;
        float v = fmaxf(acc[mf][nf][reg] + b1v[nf], 0.f);
        sm.u.X[px * 136 + oc] = f2bf(v);
      }
    }
  __syncthreads();
  for (int idx = t; idx < 1440; idx += 256) {
    int o = idx / 160, px = idx - 160 * o;
    const float* wr = sm.w9[o];
    float s = 0.f;
    #pragma unroll 4
    for (int c8 = 0; c8 < 16; ++c8) {
      short8 xv = *(const short8*)&sm.u.X[px * 136 + c8 * 8];
      #pragma unroll
      for (int j = 0; j < 8; ++j) {
        float xf = __uint_as_float(((unsigned)(unsigned short)xv[j]) << 16);
        s = fmaf(xf, wr[c8 * 8 + j], s);
      }
    }
    scoresU[(size_t)n * kM + ((size_t)h * kW + px) * 9 + o] = ordf(s + cb[o]);
  }
}

// ==== screen S1: 16-bit-key histogram, 30 blocks/image =====================
__global__ __launch_bounds__(256) void hist_kernel(
    const unsigned* __restrict__ scoresU, unsigned* __restrict__ hist16)
{
  const int img = blockIdx.y;
  const unsigned* sc = scoresU + (size_t)img * kM;
  unsigned* hg = hist16 + (size_t)img * 65536;
  const int base = blockIdx.x * 7680 + (int)threadIdx.x;
  #pragma unroll 6
  for (int k = 0; k < 30; ++k) {
    unsigned u = sc[base + k * 256];
    atomicAdd(&hg[u >> 16], 1u);
  }
}

// ==== screen S2: exact 16-bit threshold via suffix scan ====================
__global__ __launch_bounds__(1024) void thr_kernel(
    const unsigned* __restrict__ hist16, unsigned* __restrict__ thrG)
{
  const int img = blockIdx.x;
  const unsigned* hg = hist16 + (size_t)img * 65536;
  __shared__ unsigned ss[1024];
  __shared__ int schunk;
  const int t = threadIdx.x;
  unsigned psum = 0;
  #pragma unroll 8
  for (int j = 0; j < 64; ++j) psum += hg[t * 64 + j];
  ss[t] = psum;
  __syncthreads();
  // suffix scan: ss[t] = sum_{j>=t} psum[j]
  for (int off = 1; off < 1024; off <<= 1) {
    unsigned v = (t + off < 1024) ? ss[t + off] : 0u;
    __syncthreads();
    ss[t] += v;
    __syncthreads();
  }
  unsigned below = (t + 1 < 1024) ? ss[t + 1] : 0u;
  if (ss[t] >= (unsigned)kScr && below < (unsigned)kScr) schunk = t;
  __syncthreads();
  if (t == 0) {
    int ck = schunk;
    unsigned cum = (ck + 1 < 1024) ? ss[ck + 1] : 0u;
    int b = ck * 64 + 63;
    for (; b >= ck * 64; --b) {
      unsigned hh = hg[b];
      if (cum + hh >= (unsigned)kScr) break;
      cum += hh;
    }
    thrG[img * 8 + 0] = (unsigned)b;          // T16
    thrG[img * 8 + 1] = (unsigned)kScr - cum; // needB
  }
}

// ==== screen S3: collect  (>T16 -> bitmap; ==T16 -> eq list) ===============
__global__ __launch_bounds__(256) void collect_kernel(
    const unsigned* __restrict__ scoresU, const unsigned* __restrict__ thrG,
    unsigned* __restrict__ bmG, unsigned* __restrict__ eqbuf)
{
  const int img = blockIdx.y;
  const unsigned* sc = scoresU + (size_t)img * kM;
  unsigned* bm = bmG + (size_t)img * kBmW;
  unsigned* eq = eqbuf + (size_t)img * 8192;
  unsigned* cnt = (unsigned*)&((unsigned*)thrG)[img * 8 + 2];
  const unsigned T16 = thrG[img * 8 + 0];
  const int base = blockIdx.x * 7680 + (int)threadIdx.x;
  #pragma unroll 6
  for (int k = 0; k < 30; ++k) {
    int i = base + k * 256;
    unsigned tb = sc[i] >> 16;
    if (tb > T16) {
      atomicOr(&bm[(unsigned)i >> 5], 1u << (i & 31));
    } else if (tb == T16) {
      unsigned p = atomicAdd(cnt, 1u);
      if (p < 8192u) eq[p] = (unsigned)i;
    }
  }
}

// ==== screen S4: exact select among eq + ascending emit ====================
__global__ __launch_bounds__(1024) void final_kernel(
    const unsigned* __restrict__ scoresU, const unsigned* __restrict__ thrG,
    const unsigned* __restrict__ bmG, const unsigned* __restrict__ eqbuf,
    unsigned* __restrict__ candIdx)
{
  const int img = blockIdx.x;
  const unsigned* sc = scoresU + (size_t)img * kM;
  const unsigned* eq = eqbuf + (size_t)img * 8192;
  __shared__ unsigned bitmap[kBmW];   // 28800 B
  __shared__ unsigned ssum[1024];
  __shared__ unsigned hist[256];
  __shared__ unsigned shv[8];
  const int t = threadIdx.x;
  for (int i = t; i < kBmW; i += 1024) bitmap[i] = bmG[(size_t)img * kBmW + i];
  if (t < 8) shv[t] = 0;
  __syncthreads();
  const unsigned T16 = thrG[img * 8 + 0];
  const unsigned needB = thrG[img * 8 + 1];
  const unsigned ceRaw = thrG[img * 8 + 2];
  const unsigned ce = ceRaw > 8192u ? 8192u : ceRaw;
  if (ceRaw <= 8192u) {
    // exact: top-needB among eq by low-16 desc (2x8-bit radix)
    if (t == 0) { shv[0] = 0; shv[1] = 0; shv[2] = needB; }
    __syncthreads();
    for (int pass = 0; pass < 2; ++pass) {
      const int shift = 8 - pass * 8;
      if (t < 256) hist[t] = 0;
      __syncthreads();
      unsigned pre = shv[0], pm = shv[1];
      for (unsigned i = t; i < ce; i += 1024) {
        unsigned ul = sc[eq[i]] & 0xFFFFu;
        if ((ul & pm) == pre) atomicAdd(&hist[(ul >> shift) & 255u], 1u);
      }
      __syncthreads();
      if (t == 0) {
        unsigned c = 0; int b = 255;
        for (; b > 0; --b) { unsigned hh = hist[b]; if (c + hh >= shv[2]) break; c += hh; }
        shv[0] |= ((unsigned)b) << shift;
        shv[1] |= 0xFFu << shift;
        shv[2] -= c;
      }
      __syncthreads();
    }
    const unsigned Tlow = shv[0];
    const unsigned needT = shv[2];
    for (unsigned i = t; i < ce; i += 1024) {
      unsigned idx = eq[i];
      if ((sc[idx] & 0xFFFFu) > Tlow)
        atomicOr(&bitmap[idx >> 5], 1u << (idx & 31));
    }
    // tie: needT smallest indices among == Tlow (3x6-bit index radix)
    if (t == 0) { shv[3] = 0; shv[4] = 0; shv[5] = needT; }
    __syncthreads();
    for (int pass = 0; pass < 3; ++pass) {
      const int shift = 12 - pass * 6;
      if (t < 64) hist[t] = 0;
      __syncthreads();
      unsigned pre = shv[3], pm = shv[4];
      for (unsigned i = t; i < ce; i += 1024) {
        unsigned idx = eq[i];
        if ((sc[idx] & 0xFFFFu) == Tlow && (idx & pm) == pre)
          atomicAdd(&hist[(idx >> shift) & 63u], 1u);
      }
      __syncthreads();
      if (t == 0) {
        unsigned c = 0; int b = 0;
        for (; b < 63; ++b) { unsigned hh = hist[b]; if (c + hh >= shv[5]) break; c += hh; }
        shv[3] |= ((unsigned)b) << shift;
        shv[4] |= 63u << shift;
        shv[5] -= c;
      }
      __syncthreads();
    }
    const unsigned tau = shv[3];
    for (unsigned i = t; i < ce; i += 1024) {
      unsigned idx = eq[i];
      if ((sc[idx] & 0xFFFFu) == Tlow && idx <= tau)
        atomicOr(&bitmap[idx >> 5], 1u << (idx & 31));
    }
    __syncthreads();
  } else {
    // exact full-scan fallback (never on benign inputs)
    if (t == 0) { shv[0] = 0; shv[1] = 0; shv[2] = needB; }
    __syncthreads();
    for (int pass = 0; pass < 2; ++pass) {
      const int shift = 8 - pass * 8;
      if (t < 256) hist[t] = 0;
      __syncthreads();
      unsigned pre = shv[0], pm = shv[1];
      for (int i = t; i < kM; i += 1024) {
        unsigned u = sc[i];
        if ((u >> 16) == T16) {
          unsigned ul = u & 0xFFFFu;
          if ((ul & pm) == pre) atomicAdd(&hist[(ul >> shift) & 255u], 1u);
        }
      }
      __syncthreads();
      if (t == 0) {
        unsigned c = 0; int b = 255;
        for (; b > 0; --b) { unsigned hh = hist[b]; if (c + hh >= shv[2]) break; c += hh; }
        shv[0] |= ((unsigned)b) << shift;
        shv[1] |= 0xFFu << shift;
        shv[2] -= c;
      }
      __syncthreads();
    }
    const unsigned Tlow = shv[0];
    const unsigned needT = shv[2];
    for (int i = t; i < kM; i += 1024) {
      unsigned u = sc[i];
      if ((u >> 16) == T16 && (u & 0xFFFFu) > Tlow)
        atomicOr(&bitmap[(unsigned)i >> 5], 1u << (i & 31));
    }
    if (t == 0) { shv[3] = 0; shv[4] = 0; shv[5] = needT; }
    __syncthreads();
    for (int pass = 0; pass < 3; ++pass) {
      const int shift = 12 - pass * 6;
      if (t < 64) hist[t] = 0;
      __syncthreads();
      unsigned pre = shv[3], pm = shv[4];
      for (int i = t; i < kM; i += 1024) {
        unsigned u = sc[i];
        if ((u >> 16) == T16 && (u & 0xFFFFu) == Tlow &&
            (((unsigned)i) & pm) == pre)
          atomicAdd(&hist[(((unsigned)i) >> shift) & 63u], 1u);
      }
      __syncthreads();
      if (t == 0) {
        unsigned c = 0; int b = 0;
        for (; b < 63; ++b) { unsigned hh = hist[b]; if (c + hh >= shv[5]) break; c += hh; }
        shv[3] |= ((unsigned)b) << shift;
        shv[4] |= 63u << shift;
        shv[5] -= c;
      }
      __syncthreads();
    }
    const unsigned tau = shv[3];
    for (int i = t; i < kM; i += 1024) {
      unsigned u = sc[i];
      if ((u >> 16) == T16 && (u & 0xFFFFu) == Tlow && (unsigned)i <= tau)
        atomicOr(&bitmap[(unsigned)i >> 5], 1u << (i & 31));
    }
    __syncthreads();
  }
  // emit ascending: popcount + Hillis-Steele block scan
  unsigned cl = 0;
  #pragma unroll
  for (int k = 0; k < 8; ++k) {
    int wi = t * 8 + k;
    if (wi < kBmW) cl += (unsigned)__popc(bitmap[wi]);
  }
  ssum[t] = cl;
  __syncthreads();
  for (int o2 = 1; o2 < 1024; o2 <<= 1) {
    unsigned v = (t >= o2) ? ssum[t - o2] : 0u;
    __syncthreads();
    ssum[t] += v;
    __syncthreads();
  }
  unsigned off = ssum[t] - cl;
  unsigned* tout = candIdx + (size_t)img * kScr;
  #pragma unroll
  for (int k = 0; k < 8; ++k) {
    int wi = t * 8 + k;
    if (wi < kBmW) {
      unsigned wv = bitmap[wi];
      while (wv) {
        int b = __ffs(wv) - 1;
        wv &= wv - 1;
        tout[off++] = (unsigned)(wi * 32 + b);
      }
    }
  }
}

// ==== f64 refine: 6 cands/block; f32 patch in LDS (lossless), cvt at use.
__global__ __launch_bounds__(256) void refine_kernel(
    const float* __restrict__ feat, const float* __restrict__ wT4,
    const float* __restrict__ b1, const float* __restrict__ cw,
    const float* __restrict__ cb, const float* __restrict__ bwp,
    const float* __restrict__ bbp, const unsigned* __restrict__ candIdx,
    double* __restrict__ rsc, double* __restrict__ rdd, int sBase)
{
  const int img = blockIdx.y;
  const int s0 = sBase + blockIdx.x * 6;
  const int t = threadIdx.x;
  __shared__ __align__(16) float patch[6][1160];   // 27840 B
  __shared__ double xa[128][6];                    // 6144 B
  __shared__ double dd[6][5];
  __shared__ unsigned meta[6];
  if (t < 6) {
    int s = s0 + t;
    meta[t] = candIdx[(size_t)img * kScr + (s < kScr ? s : kScr - 1)];
  }
  __syncthreads();
  const float* fb = feat + (size_t)img * 128 * kHW;
  for (int e = t; e < 6 * 384; e += 256) {
    int rr = e / 384, q = e % 384, ic = q / 3, ky = q % 3;
    unsigned idx = meta[rr];
    int pix = (int)(idx / 9u);
    int hh = pix / kW - 1 + ky, ww = pix % kW;
    float v0 = 0.f, v1 = 0.f, v2 = 0.f;
    if ((unsigned)hh < (unsigned)kH) {
      const float* row = fb + ((size_t)ic * kH + hh) * kW + ww;
      if (ww - 1 >= 0) v0 = row[-1];
      v1 = row[0];
      if (ww + 1 < kW) v2 = row[1];
    }
    float* pp = &patch[rr][ic * 9 + ky * 3];
    pp[0] = v0; pp[1] = v1; pp[2] = v2;
  }
  __syncthreads();
  const int ocb = t & 31, rh = t >> 5;   // oc = ocb + 32*k; K-eighth rh
  double acc[4][6];
  #pragma unroll
  for (int k = 0; k < 4; ++k)
    #pragma unroll
    for (int c = 0; c < 6; ++c) acc[k][c] = 0.0;
  {
    const float4* wq = reinterpret_cast<const float4*>(wT4) + (size_t)(rh * 36) * 128;
    for (int R4 = 0; R4 < 36; ++R4) {
      float4 wv0 = wq[(size_t)R4 * 128 + ocb];
      float4 wv1 = wq[(size_t)R4 * 128 + ocb + 32];
      float4 wv2 = wq[(size_t)R4 * 128 + ocb + 64];
      float4 wv3 = wq[(size_t)R4 * 128 + ocb + 96];
      double w0x = (double)wv0.x, w0y = (double)wv0.y, w0z = (double)wv0.z, w0w = (double)wv0.w;
      double w1x = (double)wv1.x, w1y = (double)wv1.y, w1z = (double)wv1.z, w1w = (double)wv1.w;
      double w2x = (double)wv2.x, w2y = (double)wv2.y, w2z = (double)wv2.z, w2w = (double)wv2.w;
      double w3x = (double)wv3.x, w3y = (double)wv3.y, w3z = (double)wv3.z, w3w = (double)wv3.w;
      const int Rp = rh * 144 + R4 * 4;
      #pragma unroll
      for (int c = 0; c < 6; ++c) {
        float4 pv = *reinterpret_cast<const float4*>(&patch[c][Rp]);
        double p0 = (double)pv.x, p1 = (double)pv.y,
               p2 = (double)pv.z, p3 = (double)pv.w;
        acc[0][c] = fma(w0x, p0, acc[0][c]);
        acc[0][c] = fma(w0y, p1, acc[0][c]);
        acc[0][c] = fma(w0z, p2, acc[0][c]);
        acc[0][c] = fma(w0w, p3, acc[0][c]);
        acc[1][c] = fma(w1x, p0, acc[1][c]);
        acc[1][c] = fma(w1y, p1, acc[1][c]);
        acc[1][c] = fma(w1z, p2, acc[1][c]);
        acc[1][c] = fma(w1w, p3, acc[1][c]);
        acc[2][c] = fma(w2x, p0, acc[2][c]);
        acc[2][c] = fma(w2y, p1, acc[2][c]);
        acc[2][c] = fma(w2z, p2, acc[2][c]);
        acc[2][c] = fma(w2w, p3, acc[2][c]);
        acc[3][c] = fma(w3x, p0, acc[3][c]);
        acc[3][c] = fma(w3y, p1, acc[3][c]);
        acc[3][c] = fma(w3z, p2, acc[3][c]);
        acc[3][c] = fma(w3w, p3, acc[3][c]);
      }
    }
  }
  #pragma unroll
  for (int g = 0; g < 8; ++g) {
    if (rh == g) {
      #pragma unroll
      for (int k = 0; k < 4; ++k)
        #pragma unroll
        for (int c = 0; c < 6; ++c) {
          if (g == 0) xa[ocb + 32 * k][c] = acc[k][c];
          else        xa[ocb + 32 * k][c] += acc[k][c];
        }
    }
    __syncthreads();
  }
  if (rh == 0) {
    #pragma unroll
    for (int k = 0; k < 4; ++k) {
      double bb1 = (double)b1[ocb + 32 * k];
      #pragma unroll
      for (int c = 0; c < 6; ++c)
        xa[ocb + 32 * k][c] = fmax(xa[ocb + 32 * k][c] + bb1, 0.0);
    }
  }
  __syncthreads();
  if (t < 30) {
    int rr = t % 6, j = t / 6;   // j in 0..4 (4 deltas + 1 score)
    unsigned idx = meta[rr];
    int a = (int)(idx % 9u);
    const float* wr = (j < 4) ? (bwp + (size_t)(a * 4 + j) * 128)
                              : (cw + (size_t)a * 128);
    double s = 0.0;
    for (int c = 0; c < 128; ++c) s = fma((double)wr[c], xa[c][rr], s);
    dd[rr][j] = s + (double)((j < 4) ? bbp[a * 4 + j] : cb[a]);
  }
  __syncthreads();
  if (t < 6 && s0 + t < kScr) {
    size_t s = (size_t)img * kScr + s0 + t;
    rsc[s] = dd[t][4];
    double* rd = rdd + s * 4;
    rd[0] = dd[t][0]; rd[1] = dd[t][1]; rd[2] = dd[t][2]; rd[3] = dd[t][3];
  }
}

// == exact top-6000 select + sort (f64 desc, anchor-idx asc) + decode ======
__global__ __launch_bounds__(1024) void select_sort_decode_kernel(
    const double* __restrict__ rsc, const double* __restrict__ rdd,
    const unsigned* __restrict__ candIdx, const int* __restrict__ imgsz,
    double* __restrict__ cand)
{
  const int img = blockIdx.x;
  const int t = threadIdx.x;
  __shared__ uint64_t k64[8192];
  __shared__ unsigned id32[8192];   // (anchorIdx<<13) | slot
  for (int j = t; j < 8192; j += 1024) {
    if (j < kScr) {
      k64[j] = ordd(rsc[(size_t)img * kScr + j]);
      id32[j] = (candIdx[(size_t)img * kScr + j] << 13) | (unsigned)j;
    } else { k64[j] = 0; id32[j] = 0xFFFFFFFFu; }
  }
  __syncthreads();
  for (unsigned kk = 2; kk <= 8192; kk <<= 1) {
    for (unsigned jj = kk >> 1; jj > 0; jj >>= 1) {
      for (unsigned i = t; i < 8192; i += 1024) {
        unsigned ixj = i ^ jj;
        if (ixj > i) {
          uint64_t ka = k64[i], kb = k64[ixj];
          unsigned ia = id32[i], ib = id32[ixj];
          bool desc = ((i & kk) == 0);
          bool amis = (ka < kb) || (ka == kb && ia > ib);
          if (desc ? amis : !amis) {
            k64[i] = kb; k64[ixj] = ka;
            id32[i] = ib; id32[ixj] = ia;
          }
        }
      }
      __syncthreads();
    }
  }
  double* cx1 = cand + (size_t)img * 6 * kCand;
  double* cy1 = cx1 + kCand; double* cx2 = cy1 + kCand; double* cy2 = cx2 + kCand;
  double* car = cy2 + kCand; double* csc = car + kCand;
  const double img_f = (double)imgsz[0];
  const double stride = floor(img_f / (double)kW + 0.5);
  for (int r = t; r < kCand; r += 1024) {
    if (r < kPre) {
      unsigned id = id32[r];
      unsigned slot = id & 8191u;
      unsigned aidx = id >> 13;
      int a = (int)(aidx % 9u);
      int pix = (int)(aidx / 9u);
      int hh = pix / kW, ww = pix % kW;
      double sx = (double)ww * stride, sy = (double)hh * stride;
      double hwd = (double)c_hw[a], hhd = (double)c_hh[a];
      double a0 = sx - hwd, a1 = sy - hhd, a2 = sx + hwd, a3 = sy + hhd;
      double wa = a2 - a0, ha = a3 - a1;
      double cxa = a0 + 0.5 * wa, cya = a1 + 0.5 * ha;
      const double* d = rdd + ((size_t)img * kScr + slot) * 4;
      double dx = d[0], dy = d[1];
      double dw = fmin(d[2], kClampD), dh = fmin(d[3], kClampD);
      double cx = dx * wa + cxa, cy = dy * ha + cya;
      double bw2 = exp(dw) * wa, bh2 = exp(dh) * ha;
      double x1 = cx - 0.5 * bw2, y1 = cy - 0.5 * bh2;
      double x2 = cx + 0.5 * bw2, y2 = cy + 0.5 * bh2;
      x1 = fmin(fmax(x1, 0.0), img_f); y1 = fmin(fmax(y1, 0.0), img_f);
      x2 = fmin(fmax(x2, 0.0), img_f); y2 = fmin(fmax(y2, 0.0), img_f);
      cx1[r] = x1; cy1[r] = y1; cx2[r] = x2; cy2[r] = y2;
      car[r] = (x2 - x1) * (y2 - y1);
      csc[r] = rsc[(size_t)img * kScr + slot];
    } else {
      cx1[r] = 0.0; cy1[r] = 0.0; cx2[r] = 0.0; cy2[r] = 0.0;
      car[r] = 0.0; csc[r] = -1e9;
    }
  }
}

// ==== NMS mask: f32 fast path + rigorous f64 fallback (|lhs| < 32) ========
__global__ __launch_bounds__(64) void mask_kernel(
    const double* __restrict__ cand, uint64_t* __restrict__ mask)
{
  const int img = blockIdx.z, bi = blockIdx.y, b8 = blockIdx.x;
  if (bi >= (b8 + 1) * 8) return;
  const int i = bi * 64 + (int)threadIdx.x;
  const double* cx1 = cand + (size_t)img * 6 * kCand;
  const double* cy1 = cx1 + kCand; const double* cx2 = cy1 + kCand;
  const double* cy2 = cx2 + kCand; const double* car = cy2 + kCand;
  __shared__ float jb[5][512];
  const int j0base = b8 * 512;
  for (int e = (int)threadIdx.x; e < 512; e += 64) {
    int j = j0base + e; if (j >= kCand) j = kCand - 1;
    jb[0][e] = (float)cx1[j]; jb[1][e] = (float)cy1[j];
    jb[2][e] = (float)cx2[j]; jb[3][e] = (float)cy2[j];
    jb[4][e] = (float)car[j];
  }
  const double x1d = cx1[i], y1d = cy1[i], x2d = cx2[i], y2d = cy2[i], ard = car[i];
  const float fx1 = (float)x1d, fy1 = (float)y1d, fx2 = (float)x2d,
              fy2 = (float)y2d, far2 = (float)ard;
  __syncthreads();
  uint64_t row[8];
  #pragma unroll
  for (int wi = 0; wi < 8; ++wi) {
    const int w = b8 * 8 + wi;
    uint64_t bits = 0;
    if (w < kWords) {
      const int e0 = wi * 64;
      uint64_t amb = 0;
      for (int jj = 0; jj < 64; ++jj) {
        const int e = e0 + jj;
        float ix1 = fmaxf(fx1, jb[0][e]);
        float iy1 = fmaxf(fy1, jb[1][e]);
        float ix2 = fminf(fx2, jb[2][e]);
        float iy2 = fminf(fy2, jb[3][e]);
        float inter = fmaxf(ix2 - ix1, 0.f) * fmaxf(iy2 - iy1, 0.f);
        float den = fmaxf(far2 + jb[4][e] - inter, 1e-9f);
        float lhs = fmaf(-0.7f, den, inter);
        bits |= (uint64_t)(lhs > 0.f) << jj;
        amb  |= (uint64_t)(fabsf(lhs) < 32.f) << jj;
      }
      while (amb) {
        int jj = __ffsll((unsigned long long)amb) - 1;
        amb &= amb - 1;
        int j = j0base + wi * 64 + jj;
        double ix1 = fmax(x1d, cx1[j]);
        double iy1 = fmax(y1d, cy1[j]);
        double ix2 = fmin(x2d, cx2[j]);
        double iy2 = fmin(y2d, cy2[j]);
        double inter = fmax(ix2 - ix1, 0.0) * fmax(iy2 - iy1, 0.0);
        double den = fmax(ard + car[j] - inter, 1e-9);
        uint64_t bit = (uint64_t)(inter > 0.7 * den);
        bits = (bits & ~(1ull << jj)) | (bit << jj);
      }
    }
    row[wi] = bits;
  }
  uint64_t* rp = mask + ((size_t)img * kCand + i) * kRowW + b8 * 8;
  #pragma unroll
  for (int wi = 0; wi < 8; ++wi)
    if (b8 * 8 + wi < kWords) rp[wi] = row[wi];
}

// ===== greedy scan: 4 waves, double-buffered staging =======================
__global__ __launch_bounds__(256) void scan_kernel(
    const double* __restrict__ cand, const uint64_t* __restrict__ mask,
    float* __restrict__ out)
{
  const int img = blockIdx.x;
  const int t = threadIdx.x;
  const int lane = t & 63, wave = t >> 6;
  __shared__ uint64_t rows[2][64][96];    // 98304 B
  __shared__ unsigned short keep[kPost];  // 2000 B
  __shared__ int sh_cnt;
  if (t == 0) sh_cnt = 0;
  const uint64_t* mb = mask + (size_t)img * kCand * kRowW;
  const bool hiValid = (lane + 64 < kWords);
  uint64_t remLo = 0, remHi = 0;
  int cnt = 0;

  {
    uint64_t tl[16], th[16];
    #pragma unroll
    for (int i = 0; i < 16; ++i) {
      const uint64_t* rp = mb + (size_t)(wave + 4 * i) * kRowW;
      tl[i] = rp[lane];
      th[i] = hiValid ? rp[lane + 64] : 0ull;
    }
    #pragma unroll
    for (int i = 0; i < 16; ++i) {
      int r = wave + 4 * i;
      rows[0][r][lane] = tl[i];
      if (hiValid) rows[0][r][lane + 64] = th[i];
    }
  }
  __syncthreads();

  int cur = 0;
  for (int b = 0; b < kWords; ++b) {
    if (wave != 0) {
      int nb = b + 1;
      if (nb < kWords) {
        const uint64_t* rb = mb + (size_t)nb * 64 * kRowW;
        uint64_t tl[22], th[22];
        #pragma unroll
        for (int i = 0; i < 22; ++i) {
          int r = (wave - 1) + 3 * i;
          if (r < 64) {
            const uint64_t* rp = rb + (size_t)r * kRowW;
            tl[i] = rp[lane];
            th[i] = hiValid ? rp[lane + 64] : 0ull;
          }
        }
        #pragma unroll
        for (int i = 0; i < 22; ++i) {
          int r = (wave - 1) + 3 * i;
          if (r < 64) {
            rows[cur ^ 1][r][lane] = tl[i];
            if (hiValid) rows[cur ^ 1][r][lane + 64] = th[i];
          }
        }
      }
    } else {
      uint64_t rw = (b < 64) ? remLo : remHi;
      uint64_t aliveW = ~shfl64(rw, b & 63);
      if (b == kWords - 1) aliveW &= (1ull << 48) - 1ull;   // kPre = 93*64+48
      while (aliveW != 0ull && cnt < kPost) {
        int i = __ffsll((unsigned long long)aliveW) - 1;
        if (lane == 0) keep[cnt] = (unsigned short)(b * 64 + i);
        ++cnt;
        remLo |= rows[cur][i][lane];
        if (hiValid) remHi |= rows[cur][i][lane + 64];
        aliveW &= ~(1ull << i);
        aliveW &= ~rows[cur][i][b];
      }
      if (lane == 0) sh_cnt = cnt;
    }
    __syncthreads();
    if (sh_cnt >= kPost) break;
    cur ^= 1;
  }

  __syncthreads();
  const int fcnt = sh_cnt;
  const double* cx1 = cand + (size_t)img * 6 * kCand;
  const double* cy1 = cx1 + kCand; const double* cx2 = cy1 + kCand;
  const double* cy2 = cx2 + kCand; const double* car = cy2 + kCand;
  const double* csc = car + kCand;
  for (int r = t; r < kPost; r += 256) {
    float b0 = 0.f, b1v = 0.f, b2 = 0.f, b3 = 0.f, s = -1e9f;
    if (r < fcnt) {
      int i = keep[r];
      b0 = (float)cx1[i]; b1v = (float)cy1[i];
      b2 = (float)cx2[i]; b3 = (float)cy2[i]; s = (float)csc[i];
    }
    float* ob = out + ((size_t)img * kPost + r) * 4;
    ob[0] = b0; ob[1] = b1v; ob[2] = b2; ob[3] = b3;
    out[(size_t)kN * kPost * 4 + (size_t)img * kPost + r] = s;
  }
}

}  // namespace

extern "C" void kernel_launch(void* const* d_in, const int* in_sizes, int n_in,
                              void* d_out, int out_size, void* d_ws, size_t ws_size,
                              hipStream_t stream) {
  const float* feat = (const float*)d_in[0];
  const float* w1   = (const float*)d_in[1];
  const float* b1   = (const float*)d_in[2];
  const float* cw   = (const float*)d_in[3];
  const float* cb   = (const float*)d_in[4];
  const float* bwp  = (const float*)d_in[5];
  const float* bbp  = (const float*)d_in[6];
  const int*   imgsz = (const int*)d_in[7];
  float* out = (float*)d_out;
  char* ws = (char*)d_ws;

  size_t off = 0;
  auto take = [&](size_t sz) { size_t o = off; off += (sz + 255) & ~(size_t)255; return o; };
  size_t oWT4    = take((size_t)1152 * 128 * 4);
  size_t oWBf    = take((size_t)9 * 128 * 128 * 2);
  size_t oScrU   = take((size_t)kN * kM * 4);
  size_t oCandI  = take((size_t)kN * kScr * 4);
  size_t oEq     = take((size_t)kN * 8192 * 4);
  size_t oRsc    = take((size_t)kN * kScr * 8);
  size_t oRdd    = take((size_t)kN * kScr * 4 * 8);
  size_t oCand   = take((size_t)kN * 6 * kCand * 8);
  size_t oMask   = take((size_t)kN * kCand * kRowW * 8);
  size_t oHist16 = take((size_t)kN * 65536 * 4);
  size_t oBmG    = take((size_t)kN * kBmW * 4);
  size_t oThr    = take((size_t)kN * 8 * 4);
  if (ws_size < off) return;

  float*    wT4     = (float*)(ws + oWT4);
  short*    wBf     = (short*)(ws + oWBf);
  unsigned* scoresU = (unsigned*)(ws + oScrU);
  unsigned* candI   = (unsigned*)(ws + oCandI);
  unsigned* eqb     = (unsigned*)(ws + oEq);
  double*   rsc     = (double*)(ws + oRsc);
  double*   rdd     = (double*)(ws + oRdd);
  double*   cand    = (double*)(ws + oCand);
  uint64_t* mask    = (uint64_t*)(ws + oMask);
  unsigned* hist16  = (unsigned*)(ws + oHist16);
  unsigned* bmG     = (unsigned*)(ws + oBmG);
  unsigned* thrG    = (unsigned*)(ws + oThr);

  hipLaunchKernelGGL(prep_kernel, dim3(576), dim3(256), 0, stream, w1, wT4, wBf);
  hipLaunchKernelGGL(zero_kernel, dim3((kN * 65536 + 255) / 256), dim3(256), 0,
                     stream, hist16, bmG, thrG);
  hipLaunchKernelGGL(conv_mfma_kernel, dim3(kH, kN), dim3(256), 0, stream,
                     feat, wBf, b1, cw, cb, scoresU);
  hipLaunchKernelGGL(hist_kernel, dim3(30, kN), dim3(256), 0, stream,
                     scoresU, hist16);
  hipLaunchKernelGGL(thr_kernel, dim3(kN), dim3(1024), 0, stream,
                     hist16, thrG);
  hipLaunchKernelGGL(collect_kernel, dim3(30, kN), dim3(256), 0, stream,
                     scoresU, thrG, bmG, eqb);
  hipLaunchKernelGGL(final_kernel, dim3(kN), dim3(1024), 0, stream,
                     scoresU, thrG, bmG, eqb, candI);
  hipLaunchKernelGGL(refine_kernel, dim3(598, kN), dim3(256), 0, stream,
                     feat, wT4, b1, cw, cb, bwp, bbp, candI, rsc, rdd, 0);
  hipLaunchKernelGGL(refine_kernel, dim3(597, kN), dim3(256), 0, stream,
                     feat, wT4, b1, cw, cb, bwp, bbp, candI, rsc, rdd, 3588);
  hipLaunchKernelGGL(select_sort_decode_kernel, dim3(kN), dim3(1024), 0, stream,
                     rsc, rdd, candI, imgsz, cand);
  hipLaunchKernelGGL(mask_kernel, dim3(12, kWords, kN), dim3(64), 0, stream,
                     cand, mask);
  hipLaunchKernelGGL(scan_kernel, dim3(kN), dim3(256), 0, stream,
                     cand, mask, out);
}